// Round 1
// baseline (13986.354 us; speedup 1.0000x reference)
//
#include <hip/hip_runtime.h>
#include <hip/hip_bf16.h>

#define B_ 2
#define L_ 512
#define Q_ 512
#define E_ 1024
#define W_ 1024
#define D_ 8
#define H_ 32
#define NH_ 16
#define HD_ 64
#define SA_ 512
#define SO_ 1024
#define V_ 8192
#define T_ 6
#define SYNH_ 2048

__device__ __forceinline__ float gelu_f(float x) {
    const float c = 0.7978845608028654f; // sqrt(2/pi)
    float x3 = x * x * x;
    return 0.5f * x * (1.0f + tanhf(c * (x + 0.044715f * x3)));
}

// ---------------- generic tiled fp32 GEMM: C = act(A@B + bias) ----------------
// A: (M,K) lda, B: (K,N) ldb, C: (M,N) ldc. M%64==0, N%64==0, K%16==0.
#define BM 64
#define BN 64
#define BK 16

__global__ __launch_bounds__(256) void gemm_f32(
    const float* __restrict__ A, int lda,
    const float* __restrict__ Bm, int ldb,
    float* __restrict__ C, int ldc,
    const float* __restrict__ bias,  // nullable
    int M, int N, int K, int act)    // act: 0 none, 1 gelu
{
    __shared__ float As[BK][BM + 4];
    __shared__ float Bs[BK][BN + 4];
    const int bm = blockIdx.y * BM;
    const int bn = blockIdx.x * BN;
    const int tid = threadIdx.x;
    const int tx = tid & 15;   // 0..15 col group
    const int ty = tid >> 4;   // 0..15 row group
    float acc[4][4] = {};

    for (int k0 = 0; k0 < K; k0 += BK) {
        {
            int row = tid >> 2;            // 0..63
            int kk = (tid & 3) * 4;        // 0,4,8,12
            const float4 a4 = *(const float4*)(A + (size_t)(bm + row) * lda + k0 + kk);
            As[kk + 0][row] = a4.x;
            As[kk + 1][row] = a4.y;
            As[kk + 2][row] = a4.z;
            As[kk + 3][row] = a4.w;
        }
        {
            int krow = tid >> 4;           // 0..15
            int col = (tid & 15) * 4;      // 0..60
            const float4 b4 = *(const float4*)(Bm + (size_t)(k0 + krow) * ldb + bn + col);
            *(float4*)&Bs[krow][col] = b4;
        }
        __syncthreads();
#pragma unroll
        for (int kk = 0; kk < BK; ++kk) {
            float a[4], b[4];
#pragma unroll
            for (int i = 0; i < 4; ++i) a[i] = As[kk][ty * 4 + i];
#pragma unroll
            for (int j = 0; j < 4; ++j) b[j] = Bs[kk][tx * 4 + j];
#pragma unroll
            for (int i = 0; i < 4; ++i)
#pragma unroll
                for (int j = 0; j < 4; ++j)
                    acc[i][j] = fmaf(a[i], b[j], acc[i][j]);
        }
        __syncthreads();
    }

#pragma unroll
    for (int i = 0; i < 4; ++i) {
        int row = bm + ty * 4 + i;
#pragma unroll
        for (int j = 0; j < 4; ++j) {
            int col = bn + tx * 4 + j;
            float v = acc[i][j];
            if (bias) v += bias[col];
            if (act == 1) v = gelu_f(v);
            C[(size_t)row * ldc + col] = v;
        }
    }
}

// ---------------- embedding gather ----------------
__global__ void gather_emb(const int* __restrict__ x, const float* __restrict__ emb,
                           float* __restrict__ out) {
    // over B*L*(E/4)
    size_t i = (size_t)blockIdx.x * 256 + threadIdx.x;
    const int e4n = E_ / 4;
    size_t row = i / e4n;
    int e4 = (int)(i % e4n);
    const float4* src = (const float4*)(emb + (size_t)x[row] * E_) + e4;
    ((float4*)out)[i] = *src;
}

// ---------------- heads reshape (+ optional RoPE) ----------------
// lin: (B,S,E) -> out: (B,NH,S,HD)
__global__ void rope_heads(const float* __restrict__ lin, float* __restrict__ out,
                           int S, int applyRope) {
    const int half = HD_ / 2;  // 32
    size_t idx = (size_t)blockIdx.x * 256 + threadIdx.x;
    size_t total = (size_t)B_ * S * NH_ * half;
    if (idx >= total) return;
    int d2 = (int)(idx % half);
    int h = (int)((idx / half) % NH_);
    int s = (int)((idx / ((size_t)half * NH_)) % S);
    int b = (int)(idx / ((size_t)half * NH_ * S));
    const float* src = lin + ((size_t)b * S + s) * E_ + h * HD_;
    float x1 = src[d2], x2 = src[d2 + half];
    float o1, o2;
    if (applyRope) {
        float invf = powf(10000.0f, -(float)d2 / (float)half);
        float ang = (float)s * invf;
        float c = cosf(ang), sn = sinf(ang);
        o1 = x1 * c - x2 * sn;
        o2 = x2 * c + x1 * sn;
    } else {
        o1 = x1; o2 = x2;
    }
    float* dst = out + (((size_t)b * NH_ + h) * S + s) * HD_;
    dst[d2] = o1;
    dst[d2 + half] = o2;
}

// ---------------- state init ----------------
__global__ void init_hist0(const float* __restrict__ z_init, float* __restrict__ hist0) {
    size_t i = (size_t)blockIdx.x * 256 + threadIdx.x;  // B*Q*W
    if (i >= (size_t)B_ * Q_ * W_) return;
    hist0[i] = z_init[i % W_];
}

__global__ void init_pah(const float* __restrict__ pah_init, float* __restrict__ pah) {
    size_t i = (size_t)blockIdx.x * 256 + threadIdx.x;  // B*Q*W*D
    if (i >= (size_t)B_ * Q_ * W_ * D_) return;
    pah[i] = pah_init[i % ((size_t)W_ * D_)];
}

// ---------------- sync computation ----------------
// hist: (Tn, B, Q, W) slices of stride B*Q*W ; out: (B,Q,S)
__global__ void sync_kernel(const float* __restrict__ hist, int Tn,
                            const int* __restrict__ idx_l, const int* __restrict__ idx_r,
                            const float* __restrict__ decay,
                            float* __restrict__ out, int S) {
    size_t i = (size_t)blockIdx.x * 256 + threadIdx.x;
    if (i >= (size_t)B_ * Q_ * S) return;
    int s = (int)(i % S);
    size_t bq = i / S;
    int wl = idx_l[s], wr = idx_r[s];
    float dc = decay[s];
    float num = 0.0f, den = 0.0f;
    for (int t = 0; t < Tn; ++t) {
        float wgt = expf(-(float)(Tn - 1 - t) * dc);
        const float* hp = hist + ((size_t)t * B_ * Q_ + bq) * W_;
        num = fmaf(wgt * hp[wl], hp[wr], num);
        den += wgt;
    }
    out[i] = num / sqrtf(den);
}

// ---------------- attention (one block per (b,h,q)) ----------------
__global__ __launch_bounds__(128) void attn_kernel(
    const float* __restrict__ qh,  // (B,NH,Q,HD)
    const float* __restrict__ kh,  // (B,NH,L,HD)
    const float* __restrict__ vh,  // (B,NH,L,HD)
    float* __restrict__ ctx)       // (B,Q,E), ctx[b][q][h*HD+d]
{
    int q = blockIdx.x, h = blockIdx.y, b = blockIdx.z;
    int tid = threadIdx.x;  // 0..127
    __shared__ float sQ[HD_];
    __shared__ float sS[L_];
    __shared__ float red[128];

    const float* qptr = qh + (((size_t)(b * NH_ + h)) * Q_ + q) * HD_;
    if (tid < HD_) sQ[tid] = qptr[tid];
    __syncthreads();

    const int kmax = q + (L_ - Q_);  // causal bound (inclusive)
    const float* kbase = kh + ((size_t)(b * NH_ + h)) * L_ * HD_;
    for (int k = tid; k < L_; k += 128) {
        float s;
        if (k <= kmax) {
            const float* kp = kbase + (size_t)k * HD_;
            float acc = 0.0f;
#pragma unroll
            for (int d = 0; d < HD_; ++d) acc = fmaf(sQ[d], kp[d], acc);
            s = acc * 0.125f;  // 1/sqrt(64)
        } else {
            s = -1e30f;
        }
        sS[k] = s;
    }
    __syncthreads();

    // max
    float m = -1e30f;
    for (int k = tid; k < L_; k += 128) m = fmaxf(m, sS[k]);
    red[tid] = m;
    __syncthreads();
    for (int s = 64; s > 0; s >>= 1) {
        if (tid < s) red[tid] = fmaxf(red[tid], red[tid + s]);
        __syncthreads();
    }
    m = red[0];
    __syncthreads();

    // exp + sum
    float sum = 0.0f;
    for (int k = tid; k < L_; k += 128) {
        float p = (k <= kmax) ? expf(sS[k] - m) : 0.0f;
        sS[k] = p;
        sum += p;
    }
    red[tid] = sum;
    __syncthreads();
    for (int s = 64; s > 0; s >>= 1) {
        if (tid < s) red[tid] += red[tid + s];
        __syncthreads();
    }
    float inv = 1.0f / red[0];
    __syncthreads();

    // output: 64 d-lanes x 2 k-halves
    int d = tid & 63;
    int halfk = tid >> 6;
    const float* vbase = vh + ((size_t)(b * NH_ + h)) * L_ * HD_;
    float acc = 0.0f;
    int k0 = halfk * (L_ / 2), k1 = k0 + (L_ / 2);
    for (int k = k0; k < k1; ++k) acc = fmaf(sS[k], vbase[(size_t)k * HD_ + d], acc);
    red[tid] = acc;
    __syncthreads();
    if (tid < 64) {
        float o = (red[tid] + red[tid + 64]) * inv;
        ctx[((size_t)b * Q_ + q) * E_ + h * HD_ + d] = o;
    }
}

// ---------------- copy z into the concat buffer's second half ----------------
__global__ void copy_z_cat(const float* __restrict__ z, float* __restrict__ cat) {
    size_t i = (size_t)blockIdx.x * 256 + threadIdx.x;  // B*Q*W
    if (i >= (size_t)B_ * Q_ * W_) return;
    size_t row = i / W_;
    int w = (int)(i % W_);
    cat[row * (E_ + W_) + E_ + w] = z[i];
}

// ---------------- pah shift + NLM ----------------
__global__ void nlm_kernel(float* __restrict__ pah,          // (B,Q,W,D)
                           const float* __restrict__ pre,    // (B,Q,W)
                           const float* __restrict__ w1,     // (W,D,H)
                           const float* __restrict__ b1,     // (W,H)
                           const float* __restrict__ w2,     // (W,H)
                           const float* __restrict__ b2,     // (W)
                           float* __restrict__ zout)         // (B,Q,W)
{
    size_t i = (size_t)blockIdx.x * 256 + threadIdx.x;  // B*Q*W
    if (i >= (size_t)B_ * Q_ * W_) return;
    int w = (int)(i % W_);
    float p[D_];
    float* pp = pah + i * D_;
#pragma unroll
    for (int d = 0; d < D_ - 1; ++d) p[d] = pp[d + 1];
    p[D_ - 1] = pre[i];
#pragma unroll
    for (int d = 0; d < D_; ++d) pp[d] = p[d];

    const float* w1p = w1 + (size_t)w * D_ * H_;
    const float* b1p = b1 + (size_t)w * H_;
    const float* w2p = w2 + (size_t)w * H_;
    float zacc = b2[w];
#pragma unroll
    for (int j = 0; j < H_; ++j) {
        float a = b1p[j];
#pragma unroll
        for (int d = 0; d < D_; ++d) a = fmaf(p[d], w1p[d * H_ + j], a);
        zacc = fmaf(gelu_f(a), w2p[j], zacc);
    }
    zout[i] = zacc;
}

// ---------------- host orchestration ----------------
static inline void launch_gemm(const float* A, int lda, const float* Bm, int ldb,
                               float* C, int ldc, const float* bias,
                               int M, int N, int K, int act, hipStream_t s) {
    dim3 g(N / BN, M / BM);
    gemm_f32<<<g, 256, 0, s>>>(A, lda, Bm, ldb, C, ldc, bias, M, N, K, act);
}

extern "C" void kernel_launch(void* const* d_in, const int* in_sizes, int n_in,
                              void* d_out, int out_size, void* d_ws, size_t ws_size,
                              hipStream_t stream) {
    const int*   x        = (const int*)d_in[0];
    // d_in[1]: num_output_q (== Q_), unused
    const float* emb      = (const float*)d_in[2];
    const float* w_kv     = (const float*)d_in[3];
    const float* w_q_sync = (const float*)d_in[4];
    const float* wq       = (const float*)d_in[5];
    const float* wk       = (const float*)d_in[6];
    const float* wv       = (const float*)d_in[7];
    const float* wo       = (const float*)d_in[8];
    const float* ws1      = (const float*)d_in[9];
    const float* bs1      = (const float*)d_in[10];
    const float* ws2      = (const float*)d_in[11];
    const float* bs2      = (const float*)d_in[12];
    const float* nlm_w1   = (const float*)d_in[13];
    const float* nlm_b1   = (const float*)d_in[14];
    const float* nlm_w2   = (const float*)d_in[15];
    const float* nlm_b2   = (const float*)d_in[16];
    const float* out_w    = (const float*)d_in[17];
    const float* out_b    = (const float*)d_in[18];
    const float* z_init   = (const float*)d_in[19];
    const float* pah_init = (const float*)d_in[20];
    const float* decay_a  = (const float*)d_in[21];
    const float* decay_o  = (const float*)d_in[22];
    const int*   idx_la   = (const int*)d_in[23];
    const int*   idx_ra   = (const int*)d_in[24];
    const int*   idx_lo   = (const int*)d_in[25];
    const int*   idx_ro   = (const int*)d_in[26];

    float* out = (float*)d_out;

    const size_t BQ  = (size_t)B_ * Q_;    // 1024
    const size_t BL  = (size_t)B_ * L_;    // 1024
    const size_t BQW = BQ * W_;            // 1,048,576

    // workspace carve
    float* p = (float*)d_ws;
    auto alloc = [&](size_t n) { float* r = p; p += n; return r; };
    float* emb_x  = alloc(BL * E_);
    float* kv     = alloc(BL * E_);
    float* k_lin  = alloc(BL * E_);
    float* v_lin  = alloc(BL * E_);
    float* kh     = alloc(BL * E_);
    float* vh     = alloc(BL * E_);
    float* q_lin  = alloc(BQ * E_);
    float* q2     = alloc(BQ * E_);
    float* qh     = alloc(BQ * E_);
    float* ctx    = alloc(BQ * E_);
    float* cat    = alloc(BQ * (E_ + W_));
    float* h1     = alloc(BQ * SYNH_);
    float* pre    = alloc(BQW);
    float* sync_a = alloc(BQ * SA_);
    float* sync_o = alloc(BQ * SO_);
    float* hist   = alloc((size_t)(T_ + 1) * BQW);
    float* pah    = alloc(BQW * D_);

    // ---- one-time precompute ----
    {
        size_t n = BL * (E_ / 4);
        gather_emb<<<(n + 255) / 256, 256, 0, stream>>>(x, emb, emb_x);
    }
    launch_gemm(emb_x, E_, w_kv, E_, kv, E_, nullptr, (int)BL, E_, E_, 0, stream);
    launch_gemm(kv, E_, wk, E_, k_lin, E_, nullptr, (int)BL, E_, E_, 0, stream);
    launch_gemm(kv, E_, wv, E_, v_lin, E_, nullptr, (int)BL, E_, E_, 0, stream);
    {
        size_t n = (size_t)B_ * L_ * NH_ * (HD_ / 2);
        rope_heads<<<(n + 255) / 256, 256, 0, stream>>>(k_lin, kh, L_, 1);
        rope_heads<<<(n + 255) / 256, 256, 0, stream>>>(v_lin, vh, L_, 0);
    }
    init_hist0<<<(BQW + 255) / 256, 256, 0, stream>>>(z_init, hist);
    init_pah<<<(BQW * D_ + 255) / 256, 256, 0, stream>>>(pah_init, pah);
    sync_kernel<<<(BQ * SA_ + 255) / 256, 256, 0, stream>>>(hist, 1, idx_la, idx_ra,
                                                            decay_a, sync_a, SA_);

    // ---- T iterations ----
    for (int t = 0; t < T_; ++t) {
        const float* z = hist + (size_t)t * BQW;

        launch_gemm(sync_a, SA_, w_q_sync, E_, q_lin, E_, nullptr, (int)BQ, E_, SA_, 0, stream);
        launch_gemm(q_lin, E_, wq, E_, q2, E_, nullptr, (int)BQ, E_, E_, 0, stream);
        {
            size_t n = (size_t)B_ * Q_ * NH_ * (HD_ / 2);
            rope_heads<<<(n + 255) / 256, 256, 0, stream>>>(q2, qh, Q_, 1);
        }
        {
            dim3 g(Q_, NH_, B_);
            attn_kernel<<<g, 128, 0, stream>>>(qh, kh, vh, ctx);
        }
        // attn_out -> cat[:, :E]
        launch_gemm(ctx, E_, wo, E_, cat, E_ + W_, nullptr, (int)BQ, E_, E_, 0, stream);
        copy_z_cat<<<(BQW + 255) / 256, 256, 0, stream>>>(z, cat);

        launch_gemm(cat, E_ + W_, ws1, SYNH_, h1, SYNH_, bs1, (int)BQ, SYNH_, E_ + W_, 1, stream);
        launch_gemm(h1, SYNH_, ws2, W_, pre, W_, bs2, (int)BQ, W_, SYNH_, 0, stream);

        float* znext = hist + (size_t)(t + 1) * BQW;
        nlm_kernel<<<(BQW + 255) / 256, 256, 0, stream>>>(pah, pre, nlm_w1, nlm_b1,
                                                          nlm_w2, nlm_b2, znext);

        int Tn = t + 2;
        if (t < T_ - 1)
            sync_kernel<<<(BQ * SA_ + 255) / 256, 256, 0, stream>>>(hist, Tn, idx_la, idx_ra,
                                                                    decay_a, sync_a, SA_);
        sync_kernel<<<(BQ * SO_ + 255) / 256, 256, 0, stream>>>(hist, Tn, idx_lo, idx_ro,
                                                                decay_o, sync_o, SO_);

        float* out_t = out + (size_t)t * BQ * V_;
        launch_gemm(sync_o, SO_, out_w, V_, out_t, V_, out_b, (int)BQ, V_, SO_, 0, stream);
    }
}

// Round 2
// 6987.003 us; speedup vs baseline: 2.0018x; 2.0018x over previous
//
#include <hip/hip_runtime.h>
#include <hip/hip_bf16.h>

#define B_ 2
#define L_ 512
#define Q_ 512
#define E_ 1024
#define W_ 1024
#define D_ 8
#define H_ 32
#define NH_ 16
#define HD_ 64
#define SA_ 512
#define SO_ 1024
#define V_ 8192
#define T_ 6
#define SYNH_ 2048

#define BQ_ 1024  // B_*Q_
#define BL_ 1024  // B_*L_

__device__ __forceinline__ float gelu_f(float x) {
    const float c = 0.7978845608028654f; // sqrt(2/pi)
    float x3 = x * x * x;
    return 0.5f * x * (1.0f + tanhf(c * (x + 0.044715f * x3)));
}

// ---------------- generic tiled fp32 GEMM: C = act(A@B + bias) ----------------
// A: (M,K) lda, B: (K,N) ldb, C: (M,N) ldc. M%64==0, N%64==0, K%16==0.
#define BM 64
#define BN 64
#define BK 16

__global__ __launch_bounds__(256) void gemm_f32(
    const float* __restrict__ A, int lda,
    const float* __restrict__ Bm, int ldb,
    float* __restrict__ C, int ldc,
    const float* __restrict__ bias,  // nullable
    int M, int N, int K, int act)    // act: 0 none, 1 gelu
{
    __shared__ float As[BK][BM + 4];
    __shared__ float Bs[BK][BN + 4];
    const int bm = blockIdx.y * BM;
    const int bn = blockIdx.x * BN;
    const int tid = threadIdx.x;
    const int tx = tid & 15;   // 0..15 col group
    const int ty = tid >> 4;   // 0..15 row group
    float acc[4][4] = {};

    for (int k0 = 0; k0 < K; k0 += BK) {
        {
            int row = tid >> 2;            // 0..63
            int kk = (tid & 3) * 4;        // 0,4,8,12
            const float4 a4 = *(const float4*)(A + (size_t)(bm + row) * lda + k0 + kk);
            As[kk + 0][row] = a4.x;
            As[kk + 1][row] = a4.y;
            As[kk + 2][row] = a4.z;
            As[kk + 3][row] = a4.w;
        }
        {
            int krow = tid >> 4;           // 0..15
            int col = (tid & 15) * 4;      // 0..60
            const float4 b4 = *(const float4*)(Bm + (size_t)(k0 + krow) * ldb + bn + col);
            *(float4*)&Bs[krow][col] = b4;
        }
        __syncthreads();
#pragma unroll
        for (int kk = 0; kk < BK; ++kk) {
            float a[4], b[4];
#pragma unroll
            for (int i = 0; i < 4; ++i) a[i] = As[kk][ty * 4 + i];
#pragma unroll
            for (int j = 0; j < 4; ++j) b[j] = Bs[kk][tx * 4 + j];
#pragma unroll
            for (int i = 0; i < 4; ++i)
#pragma unroll
                for (int j = 0; j < 4; ++j)
                    acc[i][j] = fmaf(a[i], b[j], acc[i][j]);
        }
        __syncthreads();
    }

#pragma unroll
    for (int i = 0; i < 4; ++i) {
        int row = bm + ty * 4 + i;
#pragma unroll
        for (int j = 0; j < 4; ++j) {
            int col = bn + tx * 4 + j;
            float v = acc[i][j];
            if (bias) v += bias[col];
            if (act == 1) v = gelu_f(v);
            C[(size_t)row * ldc + col] = v;
        }
    }
}

// ---------------- embedding gather ----------------
__global__ void gather_emb(const int* __restrict__ x, const float* __restrict__ emb,
                           float* __restrict__ out) {
    // over B*L*(E/4)
    size_t i = (size_t)blockIdx.x * 256 + threadIdx.x;
    const int e4n = E_ / 4;
    size_t row = i / e4n;
    int e4 = (int)(i % e4n);
    const float4* src = (const float4*)(emb + (size_t)x[row] * E_) + e4;
    ((float4*)out)[i] = *src;
}

// ---------------- heads reshape (+ optional RoPE) ----------------
// lin: (B,S,E) -> out: (B,NH,S,HD)
__global__ void rope_heads(const float* __restrict__ lin, float* __restrict__ out,
                           int S, int applyRope) {
    const int half = HD_ / 2;  // 32
    size_t idx = (size_t)blockIdx.x * 256 + threadIdx.x;
    size_t total = (size_t)B_ * S * NH_ * half;
    if (idx >= total) return;
    int d2 = (int)(idx % half);
    int h = (int)((idx / half) % NH_);
    int s = (int)((idx / ((size_t)half * NH_)) % S);
    int b = (int)(idx / ((size_t)half * NH_ * S));
    const float* src = lin + ((size_t)b * S + s) * E_ + h * HD_;
    float x1 = src[d2], x2 = src[d2 + half];
    float o1, o2;
    if (applyRope) {
        float invf = powf(10000.0f, -(float)d2 / (float)half);
        float ang = (float)s * invf;
        float c = cosf(ang), sn = sinf(ang);
        o1 = x1 * c - x2 * sn;
        o2 = x2 * c + x1 * sn;
    } else {
        o1 = x1; o2 = x2;
    }
    float* dst = out + (((size_t)b * NH_ + h) * S + s) * HD_;
    dst[d2] = o1;
    dst[d2 + half] = o2;
}

// ---------------- state init ----------------
// hist layout: (T+1, W, BQ)
__global__ void init_hist0(const float* __restrict__ z_init, float* __restrict__ hist0) {
    size_t i = (size_t)blockIdx.x * 256 + threadIdx.x;  // W*BQ
    if (i >= (size_t)W_ * BQ_) return;
    hist0[i] = z_init[i / BQ_];
}

// pah layout: (W, BQ, D)
__global__ void init_pah(const float* __restrict__ pah_init, float* __restrict__ pah) {
    size_t i = (size_t)blockIdx.x * 256 + threadIdx.x;  // W*BQ*D
    if (i >= (size_t)W_ * BQ_ * D_) return;
    int d = (int)(i % D_);
    int w = (int)(i / ((size_t)BQ_ * D_));
    pah[i] = pah_init[(size_t)w * D_ + d];
}

// ---------------- sync computation ----------------
// hist: (Tn, W, BQ) slices of stride W*BQ ; out: (BQ, S) row-major
__global__ __launch_bounds__(256) void sync_kernel(
    const float* __restrict__ hist, int Tn,
    const int* __restrict__ idx_l, const int* __restrict__ idx_r,
    const float* __restrict__ decay,
    float* __restrict__ out, int S) {
    const int s = blockIdx.y;
    const int bq = blockIdx.x * 256 + threadIdx.x;
    const int wl = idx_l[s], wr = idx_r[s];  // wave-uniform scalar loads
    const float dc = decay[s];
    float num = 0.0f, den = 0.0f;
    for (int t = 0; t < Tn; ++t) {
        float wgt = expf(-(float)(Tn - 1 - t) * dc);
        const float* hp = hist + (size_t)t * W_ * BQ_;
        num = fmaf(wgt * hp[(size_t)wl * BQ_ + bq], hp[(size_t)wr * BQ_ + bq], num);
        den += wgt;
    }
    out[(size_t)bq * S + s] = num * rsqrtf(den);
}

// ---------------- attention (one block per (b,h,q)) ----------------
__global__ __launch_bounds__(128) void attn_kernel(
    const float* __restrict__ qh,  // (B,NH,Q,HD)
    const float* __restrict__ kh,  // (B,NH,L,HD)
    const float* __restrict__ vh,  // (B,NH,L,HD)
    float* __restrict__ ctx)       // (B,Q,E), ctx[b][q][h*HD+d]
{
    int q = blockIdx.x, h = blockIdx.y, b = blockIdx.z;
    int tid = threadIdx.x;  // 0..127
    __shared__ float sQ[HD_];
    __shared__ float sS[L_];
    __shared__ float red[128];

    const float* qptr = qh + (((size_t)(b * NH_ + h)) * Q_ + q) * HD_;
    if (tid < HD_) sQ[tid] = qptr[tid];
    __syncthreads();

    const int kmax = q + (L_ - Q_);  // causal bound (inclusive)
    const float* kbase = kh + ((size_t)(b * NH_ + h)) * L_ * HD_;
    for (int k = tid; k < L_; k += 128) {
        float s;
        if (k <= kmax) {
            const float* kp = kbase + (size_t)k * HD_;
            float acc = 0.0f;
#pragma unroll
            for (int d = 0; d < HD_; ++d) acc = fmaf(sQ[d], kp[d], acc);
            s = acc * 0.125f;  // 1/sqrt(64)
        } else {
            s = -1e30f;
        }
        sS[k] = s;
    }
    __syncthreads();

    // max
    float m = -1e30f;
    for (int k = tid; k < L_; k += 128) m = fmaxf(m, sS[k]);
    red[tid] = m;
    __syncthreads();
    for (int s = 64; s > 0; s >>= 1) {
        if (tid < s) red[tid] = fmaxf(red[tid], red[tid + s]);
        __syncthreads();
    }
    m = red[0];
    __syncthreads();

    // exp + sum
    float sum = 0.0f;
    for (int k = tid; k < L_; k += 128) {
        float p = (k <= kmax) ? expf(sS[k] - m) : 0.0f;
        sS[k] = p;
        sum += p;
    }
    red[tid] = sum;
    __syncthreads();
    for (int s = 64; s > 0; s >>= 1) {
        if (tid < s) red[tid] += red[tid + s];
        __syncthreads();
    }
    float inv = 1.0f / red[0];
    __syncthreads();

    // output: 64 d-lanes x 2 k-halves
    int d = tid & 63;
    int halfk = tid >> 6;
    const float* vbase = vh + ((size_t)(b * NH_ + h)) * L_ * HD_;
    float acc = 0.0f;
    int k0 = halfk * (L_ / 2), k1 = k0 + (L_ / 2);
    for (int k = k0; k < k1; ++k) acc = fmaf(sS[k], vbase[(size_t)k * HD_ + d], acc);
    red[tid] = acc;
    __syncthreads();
    if (tid < 64) {
        float o = (red[tid] + red[tid + 64]) * inv;
        ctx[((size_t)b * Q_ + q) * E_ + h * HD_ + d] = o;
    }
}

// ---------------- copy z into the concat buffer's second half ----------------
// z layout: (W, BQ)
__global__ void copy_z_cat(const float* __restrict__ z, float* __restrict__ cat) {
    size_t i = (size_t)blockIdx.x * 256 + threadIdx.x;  // BQ*W, i = bq*W + w
    if (i >= (size_t)BQ_ * W_) return;
    size_t bq = i / W_;
    int w = (int)(i % W_);
    cat[bq * (E_ + W_) + E_ + w] = z[(size_t)w * BQ_ + bq];
}

// ---------------- pah shift + NLM ----------------
// one block per (bq-tile, w). pah: (W, BQ, D). pre: (BQ, W). zout: (W, BQ).
__global__ __launch_bounds__(256) void nlm_kernel(
    float* __restrict__ pah,
    const float* __restrict__ pre,
    const float* __restrict__ w1,     // (W, D, H)
    const float* __restrict__ b1,     // (W, H)
    const float* __restrict__ w2,     // (W, H)
    const float* __restrict__ b2,     // (W)
    float* __restrict__ zout)
{
    const int w = blockIdx.y;
    const int bq = blockIdx.x * 256 + threadIdx.x;
    const int tid = threadIdx.x;

    __shared__ float w1s[D_ * H_];  // 256
    __shared__ float b1s[H_];
    __shared__ float w2s[H_];
    w1s[tid] = w1[(size_t)w * D_ * H_ + tid];
    if (tid < H_) {
        b1s[tid] = b1[(size_t)w * H_ + tid];
        w2s[tid] = w2[(size_t)w * H_ + tid];
    }
    __syncthreads();

    float* pp = pah + ((size_t)w * BQ_ + bq) * D_;
    float4 lo = *(float4*)pp;
    float4 hi = *(float4*)(pp + 4);
    float p[D_];
    p[0] = lo.y; p[1] = lo.z; p[2] = lo.w;
    p[3] = hi.x; p[4] = hi.y; p[5] = hi.z; p[6] = hi.w;
    p[7] = pre[(size_t)bq * W_ + w];
    *(float4*)pp = make_float4(p[0], p[1], p[2], p[3]);
    *(float4*)(pp + 4) = make_float4(p[4], p[5], p[6], p[7]);

    float zacc = b2[w];
#pragma unroll
    for (int j = 0; j < H_; ++j) {
        float a = b1s[j];
#pragma unroll
        for (int d = 0; d < D_; ++d) a = fmaf(p[d], w1s[d * H_ + j], a);
        zacc = fmaf(gelu_f(a), w2s[j], zacc);
    }
    zout[(size_t)w * BQ_ + bq] = zacc;
}

// ---------------- host orchestration ----------------
static inline void launch_gemm(const float* A, int lda, const float* Bm, int ldb,
                               float* C, int ldc, const float* bias,
                               int M, int N, int K, int act, hipStream_t s) {
    dim3 g(N / BN, M / BM);
    gemm_f32<<<g, 256, 0, s>>>(A, lda, Bm, ldb, C, ldc, bias, M, N, K, act);
}

extern "C" void kernel_launch(void* const* d_in, const int* in_sizes, int n_in,
                              void* d_out, int out_size, void* d_ws, size_t ws_size,
                              hipStream_t stream) {
    const int*   x        = (const int*)d_in[0];
    // d_in[1]: num_output_q (== Q_), unused
    const float* emb      = (const float*)d_in[2];
    const float* w_kv     = (const float*)d_in[3];
    const float* w_q_sync = (const float*)d_in[4];
    const float* wq       = (const float*)d_in[5];
    const float* wk       = (const float*)d_in[6];
    const float* wv       = (const float*)d_in[7];
    const float* wo       = (const float*)d_in[8];
    const float* ws1      = (const float*)d_in[9];
    const float* bs1      = (const float*)d_in[10];
    const float* ws2      = (const float*)d_in[11];
    const float* bs2      = (const float*)d_in[12];
    const float* nlm_w1   = (const float*)d_in[13];
    const float* nlm_b1   = (const float*)d_in[14];
    const float* nlm_w2   = (const float*)d_in[15];
    const float* nlm_b2   = (const float*)d_in[16];
    const float* out_w    = (const float*)d_in[17];
    const float* out_b    = (const float*)d_in[18];
    const float* z_init   = (const float*)d_in[19];
    const float* pah_init = (const float*)d_in[20];
    const float* decay_a  = (const float*)d_in[21];
    const float* decay_o  = (const float*)d_in[22];
    const int*   idx_la   = (const int*)d_in[23];
    const int*   idx_ra   = (const int*)d_in[24];
    const int*   idx_lo   = (const int*)d_in[25];
    const int*   idx_ro   = (const int*)d_in[26];

    float* out = (float*)d_out;

    const size_t BQ  = BQ_;
    const size_t BL  = BL_;
    const size_t BQW = BQ * W_;

    // workspace carve
    float* p = (float*)d_ws;
    auto alloc = [&](size_t n) { float* r = p; p += n; return r; };
    float* emb_x  = alloc(BL * E_);
    float* kv     = alloc(BL * E_);
    float* k_lin  = alloc(BL * E_);
    float* v_lin  = alloc(BL * E_);
    float* kh     = alloc(BL * E_);
    float* vh     = alloc(BL * E_);
    float* q_lin  = alloc(BQ * E_);
    float* q2     = alloc(BQ * E_);
    float* qh     = alloc(BQ * E_);
    float* ctx    = alloc(BQ * E_);
    float* cat    = alloc(BQ * (E_ + W_));
    float* h1     = alloc(BQ * SYNH_);
    float* pre    = alloc(BQW);
    float* sync_a = alloc(BQ * SA_);
    float* sync_o = alloc(BQ * SO_);
    float* hist   = alloc((size_t)(T_ + 1) * BQW);  // (T+1, W, BQ)
    float* pah    = alloc(BQW * D_);                // (W, BQ, D)

    // ---- one-time precompute ----
    {
        size_t n = BL * (E_ / 4);
        gather_emb<<<(n + 255) / 256, 256, 0, stream>>>(x, emb, emb_x);
    }
    launch_gemm(emb_x, E_, w_kv, E_, kv, E_, nullptr, (int)BL, E_, E_, 0, stream);
    launch_gemm(kv, E_, wk, E_, k_lin, E_, nullptr, (int)BL, E_, E_, 0, stream);
    launch_gemm(kv, E_, wv, E_, v_lin, E_, nullptr, (int)BL, E_, E_, 0, stream);
    {
        size_t n = (size_t)B_ * L_ * NH_ * (HD_ / 2);
        rope_heads<<<(n + 255) / 256, 256, 0, stream>>>(k_lin, kh, L_, 1);
        rope_heads<<<(n + 255) / 256, 256, 0, stream>>>(v_lin, vh, L_, 0);
    }
    init_hist0<<<(BQW + 255) / 256, 256, 0, stream>>>(z_init, hist);
    init_pah<<<(BQW * D_ + 255) / 256, 256, 0, stream>>>(pah_init, pah);
    {
        dim3 g(BQ_ / 256, SA_);
        sync_kernel<<<g, 256, 0, stream>>>(hist, 1, idx_la, idx_ra, decay_a, sync_a, SA_);
    }

    // ---- T iterations ----
    for (int t = 0; t < T_; ++t) {
        const float* z = hist + (size_t)t * BQW;

        launch_gemm(sync_a, SA_, w_q_sync, E_, q_lin, E_, nullptr, (int)BQ, E_, SA_, 0, stream);
        launch_gemm(q_lin, E_, wq, E_, q2, E_, nullptr, (int)BQ, E_, E_, 0, stream);
        {
            size_t n = (size_t)B_ * Q_ * NH_ * (HD_ / 2);
            rope_heads<<<(n + 255) / 256, 256, 0, stream>>>(q2, qh, Q_, 1);
        }
        {
            dim3 g(Q_, NH_, B_);
            attn_kernel<<<g, 128, 0, stream>>>(qh, kh, vh, ctx);
        }
        // attn_out -> cat[:, :E]
        launch_gemm(ctx, E_, wo, E_, cat, E_ + W_, nullptr, (int)BQ, E_, E_, 0, stream);
        copy_z_cat<<<((int)BQW + 255) / 256, 256, 0, stream>>>(z, cat);

        launch_gemm(cat, E_ + W_, ws1, SYNH_, h1, SYNH_, bs1, (int)BQ, SYNH_, E_ + W_, 1, stream);
        launch_gemm(h1, SYNH_, ws2, W_, pre, W_, bs2, (int)BQ, W_, SYNH_, 0, stream);

        float* znext = hist + (size_t)(t + 1) * BQW;
        {
            dim3 g(BQ_ / 256, W_);
            nlm_kernel<<<g, 256, 0, stream>>>(pah, pre, nlm_w1, nlm_b1, nlm_w2, nlm_b2, znext);
        }

        int Tn = t + 2;
        if (t < T_ - 1) {
            dim3 g(BQ_ / 256, SA_);
            sync_kernel<<<g, 256, 0, stream>>>(hist, Tn, idx_la, idx_ra, decay_a, sync_a, SA_);
        }
        {
            dim3 g(BQ_ / 256, SO_);
            sync_kernel<<<g, 256, 0, stream>>>(hist, Tn, idx_lo, idx_ro, decay_o, sync_o, SO_);
        }

        float* out_t = out + (size_t)t * BQ * V_;
        launch_gemm(sync_o, SO_, out_w, V_, out_t, V_, out_b, (int)BQ, V_, SO_, 0, stream);
    }
}